// Round 1
// baseline (1946.191 us; speedup 1.0000x reference)
//
#include <hip/hip_runtime.h>
#include <hip/hip_bf16.h>
#include <stdint.h>

#define T_TOK 2048
#define HDIM 1024
#define NEXP 8
#define IDIM 3584

// ws layout (bytes)
#define WS_CNT  0
#define WS_BASE 64
#define WS_TOK  128
#define WS_GW   (WS_TOK + NEXP * T_TOK * 4)
#define WS_G    (WS_GW + NEXP * T_TOK * 4)
// g: 4096 pairs x IDIM bf16 = 29,360,128 B

__device__ __forceinline__ float bf16_to_f(unsigned short u) {
    return __uint_as_float(((unsigned int)u) << 16);
}

__global__ __launch_bounds__(256) void router_kernel(
    const float* __restrict__ x, const float* __restrict__ gate_w,
    int* __restrict__ cnt, int* __restrict__ tok, float* __restrict__ gw)
{
    int t = blockIdx.x * 4 + (threadIdx.x >> 6);
    int lane = threadIdx.x & 63;
    if (t >= T_TOK) return;
    const float* xr = x + (size_t)t * HDIM;
    float part[NEXP];
#pragma unroll
    for (int e = 0; e < NEXP; e++) part[e] = 0.f;
    for (int h = lane; h < HDIM; h += 64) {
        float xv = xr[h];
#pragma unroll
        for (int e = 0; e < NEXP; e++) part[e] += xv * gate_w[e * HDIM + h];
    }
#pragma unroll
    for (int e = 0; e < NEXP; e++) {
        float v = part[e];
#pragma unroll
        for (int o = 32; o > 0; o >>= 1) v += __shfl_xor(v, o);
        part[e] = v;
    }
    if (lane == 0) {
        int i0 = 0; float v0 = part[0];
#pragma unroll
        for (int e = 1; e < NEXP; e++) if (part[e] > v0) { v0 = part[e]; i0 = e; }
        int i1 = -1; float v1 = -3.4e38f;
#pragma unroll
        for (int e = 0; e < NEXP; e++) if (e != i0 && part[e] > v1) { v1 = part[e]; i1 = e; }
        // renormalized top-2 softmax weights: softmax denominator cancels
        float d = __expf(v1 - v0);          // <= 1
        float w1v = d / (1.f + d);
        float w0v = 1.f - w1v;
        int p0 = atomicAdd(&cnt[i0], 1);
        tok[i0 * T_TOK + p0] = t; gw[i0 * T_TOK + p0] = w0v;
        int p1 = atomicAdd(&cnt[i1], 1);
        tok[i1 * T_TOK + p1] = t; gw[i1 * T_TOK + p1] = w1v;
    }
}

__global__ void scan_kernel(const int* __restrict__ cnt, int* __restrict__ base)
{
    if (threadIdx.x == 0) {
        int s = 0;
        for (int e = 0; e < NEXP; e++) { base[e] = s; s += cnt[e]; }
    }
}

// Pass 1: for each routed (token,expert) pair, g = silu(x@w1^T) * (x@w3^T), bf16 out
__global__ __launch_bounds__(256) void ffn1_kernel(
    const float* __restrict__ x,
    const float* __restrict__ w1,
    const float* __restrict__ w3,
    const int* __restrict__ cnt,
    const int* __restrict__ base,
    const int* __restrict__ tok,
    __hip_bfloat16* __restrict__ g)
{
    const int e = blockIdx.z;
    const int cntE = cnt[e];
    const int m0 = blockIdx.y * 64;
    if (m0 >= cntE) return;
    const int i0 = blockIdx.x * 64;
    const int tid = threadIdx.x;

    __shared__ float xs[64][33];
    __shared__ float w1s[64][33];
    __shared__ float w3s[64][33];

    const int lr = tid >> 3;          // 0..31 (load row)
    const int lc = (tid & 7) * 4;     // 0..28 (load col, x4 floats)
    const int tokA = tok[e * T_TOK + min(m0 + lr, cntE - 1)];
    const int tokB = tok[e * T_TOK + min(m0 + lr + 32, cntE - 1)];

    const float* w1e = w1 + (size_t)e * IDIM * HDIM;
    const float* w3e = w3 + (size_t)e * IDIM * HDIM;

    float acc1[4][4], acc3[4][4];
#pragma unroll
    for (int r = 0; r < 4; r++)
#pragma unroll
        for (int c = 0; c < 4; c++) { acc1[r][c] = 0.f; acc3[r][c] = 0.f; }

    const int ty = tid >> 4;   // 0..15 -> rows ty*4..ty*4+3
    const int tx = tid & 15;   // 0..15 -> cols tx*4..tx*4+3

    for (int k0 = 0; k0 < HDIM; k0 += 32) {
        float4 xa = *(const float4*)(x + (size_t)tokA * HDIM + k0 + lc);
        float4 xb = *(const float4*)(x + (size_t)tokB * HDIM + k0 + lc);
        float4 wa = *(const float4*)(w1e + (size_t)(i0 + lr) * HDIM + k0 + lc);
        float4 wb = *(const float4*)(w1e + (size_t)(i0 + lr + 32) * HDIM + k0 + lc);
        float4 va = *(const float4*)(w3e + (size_t)(i0 + lr) * HDIM + k0 + lc);
        float4 vb = *(const float4*)(w3e + (size_t)(i0 + lr + 32) * HDIM + k0 + lc);
        __syncthreads();
        xs[lr][lc + 0] = xa.x; xs[lr][lc + 1] = xa.y; xs[lr][lc + 2] = xa.z; xs[lr][lc + 3] = xa.w;
        xs[lr + 32][lc + 0] = xb.x; xs[lr + 32][lc + 1] = xb.y; xs[lr + 32][lc + 2] = xb.z; xs[lr + 32][lc + 3] = xb.w;
        w1s[lr][lc + 0] = wa.x; w1s[lr][lc + 1] = wa.y; w1s[lr][lc + 2] = wa.z; w1s[lr][lc + 3] = wa.w;
        w1s[lr + 32][lc + 0] = wb.x; w1s[lr + 32][lc + 1] = wb.y; w1s[lr + 32][lc + 2] = wb.z; w1s[lr + 32][lc + 3] = wb.w;
        w3s[lr][lc + 0] = va.x; w3s[lr][lc + 1] = va.y; w3s[lr][lc + 2] = va.z; w3s[lr][lc + 3] = va.w;
        w3s[lr + 32][lc + 0] = vb.x; w3s[lr + 32][lc + 1] = vb.y; w3s[lr + 32][lc + 2] = vb.z; w3s[lr + 32][lc + 3] = vb.w;
        __syncthreads();
#pragma unroll
        for (int kk = 0; kk < 32; kk++) {
            float a[4], b1v[4], b3v[4];
#pragma unroll
            for (int r = 0; r < 4; r++) a[r] = xs[ty * 4 + r][kk];
#pragma unroll
            for (int c = 0; c < 4; c++) { b1v[c] = w1s[tx * 4 + c][kk]; b3v[c] = w3s[tx * 4 + c][kk]; }
#pragma unroll
            for (int r = 0; r < 4; r++)
#pragma unroll
                for (int c = 0; c < 4; c++) {
                    acc1[r][c] = fmaf(a[r], b1v[c], acc1[r][c]);
                    acc3[r][c] = fmaf(a[r], b3v[c], acc3[r][c]);
                }
        }
    }

    const int pbase = base[e] + m0;
#pragma unroll
    for (int r = 0; r < 4; r++) {
        int m = ty * 4 + r;
        if (m0 + m < cntE) {
            __hip_bfloat16* grow = g + (size_t)(pbase + m) * IDIM + i0 + tx * 4;
#pragma unroll
            for (int c = 0; c < 4; c++) {
                float h1 = acc1[r][c];
                float h3 = acc3[r][c];
                float s = h1 / (1.f + __expf(-h1));   // silu
                grow[c] = __float2bfloat16(s * h3);
            }
        }
    }
}

// Pass 2: y = g @ w2^T, scatter out[t] += gate * y  (atomic; exactly 2 adds/elem)
__global__ __launch_bounds__(256) void ffn2_kernel(
    const __hip_bfloat16* __restrict__ g,
    const float* __restrict__ w2,
    const int* __restrict__ cnt,
    const int* __restrict__ base,
    const int* __restrict__ tok,
    const float* __restrict__ gw,
    float* __restrict__ out)
{
    const int e = blockIdx.z;
    const int cntE = cnt[e];
    const int m0 = blockIdx.y * 64;
    if (m0 >= cntE) return;
    const int h0 = blockIdx.x * 64;
    const int tid = threadIdx.x;

    __shared__ float gs[64][33];
    __shared__ float w2s[64][33];

    const int lr = tid >> 3;
    const int lc = (tid & 7) * 4;
    const int pA = base[e] + min(m0 + lr, cntE - 1);
    const int pB = base[e] + min(m0 + lr + 32, cntE - 1);
    const unsigned short* gu = (const unsigned short*)g;
    const float* w2e = w2 + (size_t)e * HDIM * IDIM;

    float acc[4][4];
#pragma unroll
    for (int r = 0; r < 4; r++)
#pragma unroll
        for (int c = 0; c < 4; c++) acc[r][c] = 0.f;

    const int ty = tid >> 4;
    const int tx = tid & 15;

    for (int k0 = 0; k0 < IDIM; k0 += 32) {
        ushort4 ga = *(const ushort4*)(gu + (size_t)pA * IDIM + k0 + lc);
        ushort4 gb = *(const ushort4*)(gu + (size_t)pB * IDIM + k0 + lc);
        float4 wa = *(const float4*)(w2e + (size_t)(h0 + lr) * IDIM + k0 + lc);
        float4 wb = *(const float4*)(w2e + (size_t)(h0 + lr + 32) * IDIM + k0 + lc);
        __syncthreads();
        gs[lr][lc + 0] = bf16_to_f(ga.x); gs[lr][lc + 1] = bf16_to_f(ga.y);
        gs[lr][lc + 2] = bf16_to_f(ga.z); gs[lr][lc + 3] = bf16_to_f(ga.w);
        gs[lr + 32][lc + 0] = bf16_to_f(gb.x); gs[lr + 32][lc + 1] = bf16_to_f(gb.y);
        gs[lr + 32][lc + 2] = bf16_to_f(gb.z); gs[lr + 32][lc + 3] = bf16_to_f(gb.w);
        w2s[lr][lc + 0] = wa.x; w2s[lr][lc + 1] = wa.y; w2s[lr][lc + 2] = wa.z; w2s[lr][lc + 3] = wa.w;
        w2s[lr + 32][lc + 0] = wb.x; w2s[lr + 32][lc + 1] = wb.y; w2s[lr + 32][lc + 2] = wb.z; w2s[lr + 32][lc + 3] = wb.w;
        __syncthreads();
#pragma unroll
        for (int kk = 0; kk < 32; kk++) {
            float a[4], b[4];
#pragma unroll
            for (int r = 0; r < 4; r++) a[r] = gs[ty * 4 + r][kk];
#pragma unroll
            for (int c = 0; c < 4; c++) b[c] = w2s[tx * 4 + c][kk];
#pragma unroll
            for (int r = 0; r < 4; r++)
#pragma unroll
                for (int c = 0; c < 4; c++) acc[r][c] = fmaf(a[r], b[c], acc[r][c]);
        }
    }

#pragma unroll
    for (int r = 0; r < 4; r++) {
        int m = ty * 4 + r;
        if (m0 + m < cntE) {
            int t = tok[e * T_TOK + m0 + m];
            float w = gw[e * T_TOK + m0 + m];
            float* orow = out + (size_t)t * HDIM + h0 + tx * 4;
#pragma unroll
            for (int c = 0; c < 4; c++) atomicAdd(&orow[c], w * acc[r][c]);
        }
    }
}

extern "C" void kernel_launch(void* const* d_in, const int* in_sizes, int n_in,
                              void* d_out, int out_size, void* d_ws, size_t ws_size,
                              hipStream_t stream) {
    const float* x      = (const float*)d_in[0];
    const float* gate_w = (const float*)d_in[1];
    const float* w1     = (const float*)d_in[2];
    const float* w2     = (const float*)d_in[3];
    const float* w3     = (const float*)d_in[4];
    float* out = (float*)d_out;
    char* ws = (char*)d_ws;
    int* cnt   = (int*)(ws + WS_CNT);
    int* base  = (int*)(ws + WS_BASE);
    int* tok   = (int*)(ws + WS_TOK);
    float* gw  = (float*)(ws + WS_GW);
    __hip_bfloat16* g = (__hip_bfloat16*)(ws + WS_G);

    hipMemsetAsync(cnt, 0, 64, stream);
    hipMemsetAsync(d_out, 0, (size_t)out_size * sizeof(float), stream);

    router_kernel<<<T_TOK / 4, 256, 0, stream>>>(x, gate_w, cnt, tok, gw);
    scan_kernel<<<1, 64, 0, stream>>>(cnt, base);
    ffn1_kernel<<<dim3(IDIM / 64, T_TOK / 64, NEXP), 256, 0, stream>>>(x, w1, w3, cnt, base, tok, g);
    ffn2_kernel<<<dim3(HDIM / 64, T_TOK / 64, NEXP), 256, 0, stream>>>(g, w2, cnt, base, tok, gw, out);
}

// Round 2
// 732.959 us; speedup vs baseline: 2.6553x; 2.6553x over previous
//
#include <hip/hip_runtime.h>
#include <stdint.h>

#define T_TOK 2048
#define HDIM 1024
#define NEXP 8
#define IDIM 3584

// ws layout (bytes)
#define WS_CNT  0
#define WS_BASE 64
#define WS_TOK  128
#define WS_GW   (WS_TOK + NEXP * T_TOK * 4)
#define WS_XB   (WS_GW + NEXP * T_TOK * 4)
#define WS_G    (WS_XB + T_TOK * HDIM * 2)
// g: 4096 pairs x IDIM bf16 = 29,360,128 B ; total ~33.7 MB

typedef __attribute__((ext_vector_type(8))) short bf16x8;
typedef __attribute__((ext_vector_type(16))) float f32x16;

__device__ __forceinline__ unsigned short f2bf(float f) {
    union { float f; unsigned int u; } a; a.f = f;
    unsigned int u = a.u;
    return (unsigned short)((u + 0x7fffu + ((u >> 16) & 1u)) >> 16);
}

__device__ __forceinline__ uint4 pack8(const float4 a, const float4 b) {
    uint4 r;
    r.x = (unsigned)f2bf(a.x) | ((unsigned)f2bf(a.y) << 16);
    r.y = (unsigned)f2bf(a.z) | ((unsigned)f2bf(a.w) << 16);
    r.z = (unsigned)f2bf(b.x) | ((unsigned)f2bf(b.y) << 16);
    r.w = (unsigned)f2bf(b.z) | ((unsigned)f2bf(b.w) << 16);
    return r;
}

__global__ __launch_bounds__(256) void xcvt_kernel(
    const float* __restrict__ x, unsigned short* __restrict__ xb)
{
    int i = (blockIdx.x * 256 + threadIdx.x) * 8;
    float4 a = *(const float4*)(x + i);
    float4 b = *(const float4*)(x + i + 4);
    *(uint4*)(xb + i) = pack8(a, b);
}

__global__ __launch_bounds__(256) void router_kernel(
    const float* __restrict__ x, const float* __restrict__ gate_w,
    int* __restrict__ cnt, int* __restrict__ tok, float* __restrict__ gw)
{
    int t = blockIdx.x * 4 + (threadIdx.x >> 6);
    int lane = threadIdx.x & 63;
    if (t >= T_TOK) return;
    const float* xr = x + (size_t)t * HDIM;
    float part[NEXP];
#pragma unroll
    for (int e = 0; e < NEXP; e++) part[e] = 0.f;
    for (int h = lane; h < HDIM; h += 64) {
        float xv = xr[h];
#pragma unroll
        for (int e = 0; e < NEXP; e++) part[e] += xv * gate_w[e * HDIM + h];
    }
#pragma unroll
    for (int e = 0; e < NEXP; e++) {
        float v = part[e];
#pragma unroll
        for (int o = 32; o > 0; o >>= 1) v += __shfl_xor(v, o);
        part[e] = v;
    }
    if (lane == 0) {
        int i0 = 0; float v0 = part[0];
#pragma unroll
        for (int e = 1; e < NEXP; e++) if (part[e] > v0) { v0 = part[e]; i0 = e; }
        int i1 = -1; float v1 = -3.4e38f;
#pragma unroll
        for (int e = 0; e < NEXP; e++) if (e != i0 && part[e] > v1) { v1 = part[e]; i1 = e; }
        float d = __expf(v1 - v0);
        float w1v = d / (1.f + d);
        float w0v = 1.f - w1v;
        int p0 = atomicAdd(&cnt[i0], 1);
        tok[i0 * T_TOK + p0] = t; gw[i0 * T_TOK + p0] = w0v;
        int p1 = atomicAdd(&cnt[i1], 1);
        tok[i1 * T_TOK + p1] = t; gw[i1 * T_TOK + p1] = w1v;
    }
}

__global__ void scan_kernel(const int* __restrict__ cnt, int* __restrict__ base)
{
    if (threadIdx.x == 0) {
        int s = 0;
        for (int e = 0; e < NEXP; e++) { base[e] = s; s += cnt[e]; }
    }
}

// ffn1: g[p, i] = silu(x@w1^T) * (x@w3^T), bf16 out. Tile 128 tok x 64 i, BK=64.
__global__ __launch_bounds__(256, 2) void ffn1_mfma(
    const unsigned short* __restrict__ xb,
    const float* __restrict__ w1,
    const float* __restrict__ w3,
    const int* __restrict__ cnt, const int* __restrict__ base,
    const int* __restrict__ tok,
    unsigned short* __restrict__ g)
{
    const int e = blockIdx.z;
    const int cntE = cnt[e];
    const int m0 = blockIdx.y * 128;
    if (m0 >= cntE) return;
    const int i0 = blockIdx.x * 64;
    const int tid = threadIdx.x;
    const int lane = tid & 63;
    const int wid = tid >> 6;

    __shared__ __align__(16) unsigned char lds[32768]; // xs 16K | w1s 8K | w3s 8K
    __shared__ int toks_s[128];
    if (tid < 128) toks_s[tid] = tok[e * T_TOK + min(m0 + tid, cntE - 1)];
    __syncthreads();

    const int rw = tid >> 3;              // staging row 0..31
    const int kc = tid & 7;               // 16B chunk in row
    const unsigned int dcol = ((unsigned)(kc * 16)) ^ ((unsigned)((rw & 7) << 4));

    int tk[4];
#pragma unroll
    for (int j = 0; j < 4; j++) tk[j] = toks_s[rw + 32 * j];

    const float* w1e = w1 + ((size_t)e * IDIM + i0) * HDIM;
    const float* w3e = w3 + ((size_t)e * IDIM + i0) * HDIM;

    const unsigned int XS = 0, W1S = 16384, W3S = 24576;

    f32x16 acc1[2], acc3[2];
#pragma unroll
    for (int i = 0; i < 2; i++)
#pragma unroll
        for (int r = 0; r < 16; r++) { acc1[i][r] = 0.f; acc3[i][r] = 0.f; }

    const int wm = (wid >> 1) * 64;       // token offset of wave
    const int wn = (wid & 1) * 32;        // i offset of wave
    const unsigned int lrow = (unsigned)(lane & 31);
    const unsigned int lswz = (lrow & 7) << 4;
    const unsigned int lkoff = (unsigned)((lane >> 5) * 16);
    const unsigned int aRow  = XS  + (wm + lrow) * 128;
    const unsigned int b1Row = W1S + (wn + lrow) * 128;
    const unsigned int b3Row = W3S + (wn + lrow) * 128;

    for (int k0 = 0; k0 < HDIM; k0 += 64) {
        uint4 xv[4]; float4 wva[2][2], wvb[2][2];
#pragma unroll
        for (int j = 0; j < 4; j++)
            xv[j] = *(const uint4*)(xb + (size_t)tk[j] * HDIM + k0 + kc * 8);
#pragma unroll
        for (int j = 0; j < 2; j++) {
            const float* s1 = w1e + (size_t)(rw + 32 * j) * HDIM + k0 + kc * 8;
            wva[j][0] = *(const float4*)s1;
            wva[j][1] = *(const float4*)(s1 + 4);
            const float* s3 = w3e + (size_t)(rw + 32 * j) * HDIM + k0 + kc * 8;
            wvb[j][0] = *(const float4*)s3;
            wvb[j][1] = *(const float4*)(s3 + 4);
        }
        __syncthreads();   // prev iter's LDS reads done
#pragma unroll
        for (int j = 0; j < 4; j++)
            *(uint4*)(lds + XS + (rw + 32 * j) * 128 + dcol) = xv[j];
#pragma unroll
        for (int j = 0; j < 2; j++) {
            *(uint4*)(lds + W1S + (rw + 32 * j) * 128 + dcol) = pack8(wva[j][0], wva[j][1]);
            *(uint4*)(lds + W3S + (rw + 32 * j) * 128 + dcol) = pack8(wvb[j][0], wvb[j][1]);
        }
        __syncthreads();
#pragma unroll
        for (int s = 0; s < 4; s++) {
            const unsigned int kb = (unsigned)(s * 32) + lkoff;
            bf16x8 a0 = *(const bf16x8*)(lds + aRow + (kb ^ lswz));
            bf16x8 a1 = *(const bf16x8*)(lds + aRow + 32 * 128 + (kb ^ lswz));
            bf16x8 b1f = *(const bf16x8*)(lds + b1Row + (kb ^ lswz));
            bf16x8 b3f = *(const bf16x8*)(lds + b3Row + (kb ^ lswz));
            acc1[0] = __builtin_amdgcn_mfma_f32_32x32x16_bf16(a0, b1f, acc1[0], 0, 0, 0);
            acc1[1] = __builtin_amdgcn_mfma_f32_32x32x16_bf16(a1, b1f, acc1[1], 0, 0, 0);
            acc3[0] = __builtin_amdgcn_mfma_f32_32x32x16_bf16(a0, b3f, acc3[0], 0, 0, 0);
            acc3[1] = __builtin_amdgcn_mfma_f32_32x32x16_bf16(a1, b3f, acc3[1], 0, 0, 0);
        }
    }

    const int pbase = base[e] + m0;
    const int colI = i0 + wn + (int)lrow;
    const int rbase = 4 * (lane >> 5);
#pragma unroll
    for (int mf = 0; mf < 2; mf++) {
#pragma unroll
        for (int r = 0; r < 16; r++) {
            int row = (r & 3) + 8 * (r >> 2) + rbase;
            int m = wm + mf * 32 + row;
            if (m0 + m < cntE) {
                float h1 = acc1[mf][r], h3 = acc3[mf][r];
                float v = (h1 / (1.f + __expf(-h1))) * h3;
                g[(size_t)(pbase + m) * IDIM + colI] = f2bf(v);
            }
        }
    }
}

// ffn2: out[t,h] += gate * (g @ w2^T). Tile 128 pairs x 128 h, BK=64 over IDIM.
__global__ __launch_bounds__(256, 2) void ffn2_mfma(
    const unsigned short* __restrict__ g,
    const float* __restrict__ w2,
    const int* __restrict__ cnt, const int* __restrict__ base,
    const int* __restrict__ tok, const float* __restrict__ gw,
    float* __restrict__ out)
{
    const int e = blockIdx.z;
    const int cntE = cnt[e];
    const int m0 = blockIdx.y * 128;
    if (m0 >= cntE) return;
    const int h0 = blockIdx.x * 128;
    const int tid = threadIdx.x;
    const int lane = tid & 63;
    const int wid = tid >> 6;

    __shared__ __align__(16) unsigned char lds[32768]; // gs 16K | w2s 16K
    __shared__ int toks_s[128];
    __shared__ float gws_s[128];
    if (tid < 128) {
        int idx = e * T_TOK + min(m0 + tid, cntE - 1);
        toks_s[tid] = tok[idx];
        gws_s[tid] = gw[idx];
    }
    __syncthreads();

    const int rw = tid >> 3;
    const int kc = tid & 7;
    const unsigned int dcol = ((unsigned)(kc * 16)) ^ ((unsigned)((rw & 7) << 4));

    size_t gp[4];
    const int be = base[e];
#pragma unroll
    for (int j = 0; j < 4; j++)
        gp[j] = (size_t)(be + min(m0 + rw + 32 * j, cntE - 1)) * IDIM;

    const float* w2e = w2 + ((size_t)e * HDIM + h0) * IDIM;

    const unsigned int GS = 0, W2S = 16384;

    f32x16 acc[2][2];
#pragma unroll
    for (int a = 0; a < 2; a++)
#pragma unroll
        for (int b = 0; b < 2; b++)
#pragma unroll
            for (int r = 0; r < 16; r++) acc[a][b][r] = 0.f;

    const int wm = (wid >> 1) * 64;
    const int wn = (wid & 1) * 64;
    const unsigned int lrow = (unsigned)(lane & 31);
    const unsigned int lswz = (lrow & 7) << 4;
    const unsigned int lkoff = (unsigned)((lane >> 5) * 16);
    const unsigned int aRow = GS  + (wm + lrow) * 128;
    const unsigned int bRow = W2S + (wn + lrow) * 128;

    for (int k0 = 0; k0 < IDIM; k0 += 64) {
        uint4 gv[4]; float4 wv[4][2];
#pragma unroll
        for (int j = 0; j < 4; j++)
            gv[j] = *(const uint4*)(g + gp[j] + k0 + kc * 8);
#pragma unroll
        for (int j = 0; j < 4; j++) {
            const float* s = w2e + (size_t)(rw + 32 * j) * IDIM + k0 + kc * 8;
            wv[j][0] = *(const float4*)s;
            wv[j][1] = *(const float4*)(s + 4);
        }
        __syncthreads();
#pragma unroll
        for (int j = 0; j < 4; j++)
            *(uint4*)(lds + GS + (rw + 32 * j) * 128 + dcol) = gv[j];
#pragma unroll
        for (int j = 0; j < 4; j++)
            *(uint4*)(lds + W2S + (rw + 32 * j) * 128 + dcol) = pack8(wv[j][0], wv[j][1]);
        __syncthreads();
#pragma unroll
        for (int s = 0; s < 4; s++) {
            const unsigned int kb = (unsigned)(s * 32) + lkoff;
            bf16x8 a0 = *(const bf16x8*)(lds + aRow + (kb ^ lswz));
            bf16x8 a1 = *(const bf16x8*)(lds + aRow + 32 * 128 + (kb ^ lswz));
            bf16x8 b0 = *(const bf16x8*)(lds + bRow + (kb ^ lswz));
            bf16x8 b1 = *(const bf16x8*)(lds + bRow + 32 * 128 + (kb ^ lswz));
            acc[0][0] = __builtin_amdgcn_mfma_f32_32x32x16_bf16(a0, b0, acc[0][0], 0, 0, 0);
            acc[0][1] = __builtin_amdgcn_mfma_f32_32x32x16_bf16(a0, b1, acc[0][1], 0, 0, 0);
            acc[1][0] = __builtin_amdgcn_mfma_f32_32x32x16_bf16(a1, b0, acc[1][0], 0, 0, 0);
            acc[1][1] = __builtin_amdgcn_mfma_f32_32x32x16_bf16(a1, b1, acc[1][1], 0, 0, 0);
        }
    }

    const int rbase = 4 * (lane >> 5);
#pragma unroll
    for (int mi = 0; mi < 2; mi++) {
#pragma unroll
        for (int r = 0; r < 16; r++) {
            int row = (r & 3) + 8 * (r >> 2) + rbase;
            int m = wm + mi * 32 + row;
            if (m0 + m < cntE) {
                int t = toks_s[m];
                float wgt = gws_s[m];
                float* orow = out + (size_t)t * HDIM + h0 + wn + (int)lrow;
                atomicAdd(&orow[0],  wgt * acc[mi][0][r]);
                atomicAdd(&orow[32], wgt * acc[mi][1][r]);
            }
        }
    }
}

extern "C" void kernel_launch(void* const* d_in, const int* in_sizes, int n_in,
                              void* d_out, int out_size, void* d_ws, size_t ws_size,
                              hipStream_t stream) {
    const float* x      = (const float*)d_in[0];
    const float* gate_w = (const float*)d_in[1];
    const float* w1     = (const float*)d_in[2];
    const float* w2     = (const float*)d_in[3];
    const float* w3     = (const float*)d_in[4];
    float* out = (float*)d_out;
    char* ws = (char*)d_ws;
    int* cnt   = (int*)(ws + WS_CNT);
    int* base  = (int*)(ws + WS_BASE);
    int* tok   = (int*)(ws + WS_TOK);
    float* gw  = (float*)(ws + WS_GW);
    unsigned short* xb = (unsigned short*)(ws + WS_XB);
    unsigned short* g  = (unsigned short*)(ws + WS_G);

    hipMemsetAsync(cnt, 0, 64, stream);
    hipMemsetAsync(d_out, 0, (size_t)out_size * sizeof(float), stream);

    xcvt_kernel<<<T_TOK * HDIM / (256 * 8), 256, 0, stream>>>(x, xb);
    router_kernel<<<T_TOK / 4, 256, 0, stream>>>(x, gate_w, cnt, tok, gw);
    scan_kernel<<<1, 64, 0, stream>>>(cnt, base);
    ffn1_mfma<<<dim3(IDIM / 64, T_TOK / 128, NEXP), 256, 0, stream>>>(xb, w1, w3, cnt, base, tok, g);
    ffn2_mfma<<<dim3(HDIM / 128, T_TOK / 128, NEXP), 256, 0, stream>>>(g, w2, cnt, base, tok, gw, out);
}

// Round 3
// 657.862 us; speedup vs baseline: 2.9584x; 1.1142x over previous
//
#include <hip/hip_runtime.h>
#include <stdint.h>

#define T_TOK 2048
#define HDIM 1024
#define NEXP 8
#define IDIM 3584
#define MAXTILE 40

// ws layout (bytes)
#define WS_CNT   0
#define WS_BASE  64
#define WS_TE    128
#define WS_TM    384
#define WS_NT    640
#define WS_TOK   704
#define WS_GW    (WS_TOK + NEXP * T_TOK * 4)
#define WS_XB    (WS_GW + NEXP * T_TOK * 4)
#define WS_G     (WS_XB + T_TOK * HDIM * 2)
// g: 4096 pairs x IDIM bf16 = 29,360,128 B ; total ~33.7 MB

typedef __attribute__((ext_vector_type(8))) short bf16x8;
typedef __attribute__((ext_vector_type(16))) float f32x16;

__device__ __forceinline__ unsigned short f2bf(float f) {
    union { float f; unsigned int u; } a; a.f = f;
    unsigned int u = a.u;
    return (unsigned short)((u + 0x7fffu + ((u >> 16) & 1u)) >> 16);
}

__device__ __forceinline__ uint4 pack8(const float4 a, const float4 b) {
    uint4 r;
    r.x = (unsigned)f2bf(a.x) | ((unsigned)f2bf(a.y) << 16);
    r.y = (unsigned)f2bf(a.z) | ((unsigned)f2bf(a.w) << 16);
    r.z = (unsigned)f2bf(b.x) | ((unsigned)f2bf(b.y) << 16);
    r.w = (unsigned)f2bf(b.z) | ((unsigned)f2bf(b.w) << 16);
    return r;
}

__global__ __launch_bounds__(256) void xcvt_kernel(
    const float* __restrict__ x, unsigned short* __restrict__ xb)
{
    int i = (blockIdx.x * 256 + threadIdx.x) * 8;
    float4 a = *(const float4*)(x + i);
    float4 b = *(const float4*)(x + i + 4);
    *(uint4*)(xb + i) = pack8(a, b);
}

__global__ __launch_bounds__(256) void router_kernel(
    const float* __restrict__ x, const float* __restrict__ gate_w,
    int* __restrict__ cnt, int* __restrict__ tok, float* __restrict__ gw)
{
    int t = blockIdx.x * 4 + (threadIdx.x >> 6);
    int lane = threadIdx.x & 63;
    if (t >= T_TOK) return;
    const float* xr = x + (size_t)t * HDIM;
    float part[NEXP];
#pragma unroll
    for (int e = 0; e < NEXP; e++) part[e] = 0.f;
    for (int h = lane; h < HDIM; h += 64) {
        float xv = xr[h];
#pragma unroll
        for (int e = 0; e < NEXP; e++) part[e] += xv * gate_w[e * HDIM + h];
    }
#pragma unroll
    for (int e = 0; e < NEXP; e++) {
        float v = part[e];
#pragma unroll
        for (int o = 32; o > 0; o >>= 1) v += __shfl_xor(v, o);
        part[e] = v;
    }
    if (lane == 0) {
        int i0 = 0; float v0 = part[0];
#pragma unroll
        for (int e = 1; e < NEXP; e++) if (part[e] > v0) { v0 = part[e]; i0 = e; }
        int i1 = -1; float v1 = -3.4e38f;
#pragma unroll
        for (int e = 0; e < NEXP; e++) if (e != i0 && part[e] > v1) { v1 = part[e]; i1 = e; }
        float d = __expf(v1 - v0);
        float w1v = d / (1.f + d);
        float w0v = 1.f - w1v;
        int p0 = atomicAdd(&cnt[i0], 1);
        tok[i0 * T_TOK + p0] = t; gw[i0 * T_TOK + p0] = w0v;
        int p1 = atomicAdd(&cnt[i1], 1);
        tok[i1 * T_TOK + p1] = t; gw[i1 * T_TOK + p1] = w1v;
    }
}

__global__ void scan_kernel(const int* __restrict__ cnt, int* __restrict__ base,
                            int* __restrict__ tileE, int* __restrict__ tileM,
                            int* __restrict__ ntot)
{
    if (threadIdx.x == 0) {
        int s = 0, nt = 0;
        for (int e = 0; e < NEXP; e++) {
            base[e] = s; s += cnt[e];
            for (int m0 = 0; m0 < cnt[e]; m0 += 128) {
                tileE[nt] = e; tileM[nt] = m0; nt++;
            }
        }
        *ntot = nt;
    }
}

// ffn1: g = silu(x@w1^T) * (x@w3^T). Tile 128 tok x 128 i, BK=64.
__global__ __launch_bounds__(256, 2) void ffn1_mfma(
    const unsigned short* __restrict__ xb,
    const float* __restrict__ w1,
    const float* __restrict__ w3,
    const int* __restrict__ cnt, const int* __restrict__ base,
    const int* __restrict__ tok,
    const int* __restrict__ tileE, const int* __restrict__ tileM,
    const int* __restrict__ ntot,
    unsigned short* __restrict__ g)
{
    const int ti = blockIdx.y;
    if (ti >= *ntot) return;
    const int e = tileE[ti];
    const int m0 = tileM[ti];
    const int cntE = cnt[e];
    const int i0 = blockIdx.x * 128;
    const int tid = threadIdx.x;
    const int lane = tid & 63;
    const int wid = tid >> 6;

    __shared__ __align__(16) unsigned char lds[49152]; // xs 16K | w1s 16K | w3s 16K
    __shared__ int toks_s[128];
    if (tid < 128) toks_s[tid] = tok[e * T_TOK + min(m0 + tid, cntE - 1)];
    __syncthreads();

    const int rw = tid >> 3;              // staging row 0..31
    const int kc = tid & 7;               // 16B chunk in row
    const unsigned int dcol = ((unsigned)(kc * 16)) ^ ((unsigned)((rw & 7) << 4));

    int tk[4];
#pragma unroll
    for (int j = 0; j < 4; j++) tk[j] = toks_s[rw + 32 * j];

    const float* w1e = w1 + ((size_t)e * IDIM + i0) * HDIM;
    const float* w3e = w3 + ((size_t)e * IDIM + i0) * HDIM;

    const unsigned int XS = 0, W1S = 16384, W3S = 32768;

    f32x16 acc1[2][2], acc3[2][2];
#pragma unroll
    for (int a = 0; a < 2; a++)
#pragma unroll
        for (int b = 0; b < 2; b++)
#pragma unroll
            for (int r = 0; r < 16; r++) { acc1[a][b][r] = 0.f; acc3[a][b][r] = 0.f; }

    const int wr = wid >> 1;              // token half (0/1)
    const int wc = wid & 1;               // i half (0/1)
    const unsigned int lrow = (unsigned)(lane & 31);
    const unsigned int lswz = (lrow & 7) << 4;
    const unsigned int hi16 = (unsigned)((lane >> 5) * 16);
    const unsigned int aBase  = XS  + (wr * 64 + lrow) * 128;
    const unsigned int b1Base = W1S + (wc * 64 + lrow) * 128;
    const unsigned int b3Base = W3S + (wc * 64 + lrow) * 128;

    for (int k0 = 0; k0 < HDIM; k0 += 64) {
        uint4 xv[4]; float4 wva[4][2], wvb[4][2];
#pragma unroll
        for (int j = 0; j < 4; j++)
            xv[j] = *(const uint4*)(xb + (size_t)tk[j] * HDIM + k0 + kc * 8);
#pragma unroll
        for (int j = 0; j < 4; j++) {
            const float* s1 = w1e + (size_t)(rw + 32 * j) * HDIM + k0 + kc * 8;
            wva[j][0] = *(const float4*)s1;
            wva[j][1] = *(const float4*)(s1 + 4);
            const float* s3 = w3e + (size_t)(rw + 32 * j) * HDIM + k0 + kc * 8;
            wvb[j][0] = *(const float4*)s3;
            wvb[j][1] = *(const float4*)(s3 + 4);
        }
        __syncthreads();   // prev iter's LDS reads done
#pragma unroll
        for (int j = 0; j < 4; j++)
            *(uint4*)(lds + XS + (rw + 32 * j) * 128 + dcol) = xv[j];
#pragma unroll
        for (int j = 0; j < 4; j++) {
            *(uint4*)(lds + W1S + (rw + 32 * j) * 128 + dcol) = pack8(wva[j][0], wva[j][1]);
            *(uint4*)(lds + W3S + (rw + 32 * j) * 128 + dcol) = pack8(wvb[j][0], wvb[j][1]);
        }
        __syncthreads();
#pragma unroll
        for (int s = 0; s < 4; s++) {
            const unsigned int off = ((unsigned)(s * 32) + hi16) ^ lswz;
            bf16x8 a0 = *(const bf16x8*)(lds + aBase + off);
            bf16x8 a1 = *(const bf16x8*)(lds + aBase + 32 * 128 + off);
            bf16x8 p0 = *(const bf16x8*)(lds + b1Base + off);
            bf16x8 p1 = *(const bf16x8*)(lds + b1Base + 32 * 128 + off);
            bf16x8 q0 = *(const bf16x8*)(lds + b3Base + off);
            bf16x8 q1 = *(const bf16x8*)(lds + b3Base + 32 * 128 + off);
            acc1[0][0] = __builtin_amdgcn_mfma_f32_32x32x16_bf16(a0, p0, acc1[0][0], 0, 0, 0);
            acc1[0][1] = __builtin_amdgcn_mfma_f32_32x32x16_bf16(a0, p1, acc1[0][1], 0, 0, 0);
            acc1[1][0] = __builtin_amdgcn_mfma_f32_32x32x16_bf16(a1, p0, acc1[1][0], 0, 0, 0);
            acc1[1][1] = __builtin_amdgcn_mfma_f32_32x32x16_bf16(a1, p1, acc1[1][1], 0, 0, 0);
            acc3[0][0] = __builtin_amdgcn_mfma_f32_32x32x16_bf16(a0, q0, acc3[0][0], 0, 0, 0);
            acc3[0][1] = __builtin_amdgcn_mfma_f32_32x32x16_bf16(a0, q1, acc3[0][1], 0, 0, 0);
            acc3[1][0] = __builtin_amdgcn_mfma_f32_32x32x16_bf16(a1, q0, acc3[1][0], 0, 0, 0);
            acc3[1][1] = __builtin_amdgcn_mfma_f32_32x32x16_bf16(a1, q1, acc3[1][1], 0, 0, 0);
        }
    }

    const int pbase = base[e] + m0;
    const int rbase = 4 * (lane >> 5);
#pragma unroll
    for (int ma = 0; ma < 2; ma++) {
#pragma unroll
        for (int r = 0; r < 16; r++) {
            int row = (r & 3) + 8 * (r >> 2) + rbase;
            int m = wr * 64 + ma * 32 + row;
            if (m0 + m < cntE) {
                unsigned short* grow = g + (size_t)(pbase + m) * IDIM + i0 + wc * 64 + lrow;
#pragma unroll
                for (int nb = 0; nb < 2; nb++) {
                    float h1 = acc1[ma][nb][r], h3 = acc3[ma][nb][r];
                    float v = (h1 / (1.f + __expf(-h1))) * h3;
                    grow[nb * 32] = f2bf(v);
                }
            }
        }
    }
}

// ffn2: out[t,h] += gate * (g @ w2^T). Tile 128 pairs x 128 h, split-K x4 over IDIM.
__global__ __launch_bounds__(256, 2) void ffn2_mfma(
    const unsigned short* __restrict__ g,
    const float* __restrict__ w2,
    const int* __restrict__ cnt, const int* __restrict__ base,
    const int* __restrict__ tok, const float* __restrict__ gw,
    const int* __restrict__ tileE, const int* __restrict__ tileM,
    const int* __restrict__ ntot,
    float* __restrict__ out)
{
    const int ti = blockIdx.y;
    if (ti >= *ntot) return;
    const int e = tileE[ti];
    const int m0 = tileM[ti];
    const int cntE = cnt[e];
    const int ks = blockIdx.x >> 3;
    const int h0 = (blockIdx.x & 7) * 128;
    const int tid = threadIdx.x;
    const int lane = tid & 63;
    const int wid = tid >> 6;

    __shared__ __align__(16) unsigned char lds[32768]; // gs 16K | w2s 16K
    __shared__ int toks_s[128];
    __shared__ float gws_s[128];
    if (tid < 128) {
        int idx = e * T_TOK + min(m0 + tid, cntE - 1);
        toks_s[tid] = tok[idx];
        gws_s[tid] = gw[idx];
    }
    __syncthreads();

    const int rw = tid >> 3;
    const int kc = tid & 7;
    const unsigned int dcol = ((unsigned)(kc * 16)) ^ ((unsigned)((rw & 7) << 4));

    size_t gp[4];
    const int be = base[e];
#pragma unroll
    for (int j = 0; j < 4; j++)
        gp[j] = (size_t)(be + min(m0 + rw + 32 * j, cntE - 1)) * IDIM;

    const float* w2e = w2 + ((size_t)e * HDIM + h0) * IDIM;

    const unsigned int GS = 0, W2S = 16384;

    f32x16 acc[2][2];
#pragma unroll
    for (int a = 0; a < 2; a++)
#pragma unroll
        for (int b = 0; b < 2; b++)
#pragma unroll
            for (int r = 0; r < 16; r++) acc[a][b][r] = 0.f;

    const int wr = wid >> 1;
    const int wc = wid & 1;
    const unsigned int lrow = (unsigned)(lane & 31);
    const unsigned int lswz = (lrow & 7) << 4;
    const unsigned int hi16 = (unsigned)((lane >> 5) * 16);
    const unsigned int aBase = GS  + (wr * 64 + lrow) * 128;
    const unsigned int bBase = W2S + (wc * 64 + lrow) * 128;

    const int kbeg = ks * (IDIM / 4);
    const int kend = kbeg + (IDIM / 4);
    for (int k0 = kbeg; k0 < kend; k0 += 64) {
        uint4 gv[4]; float4 wv[4][2];
#pragma unroll
        for (int j = 0; j < 4; j++)
            gv[j] = *(const uint4*)(g + gp[j] + k0 + kc * 8);
#pragma unroll
        for (int j = 0; j < 4; j++) {
            const float* s = w2e + (size_t)(rw + 32 * j) * IDIM + k0 + kc * 8;
            wv[j][0] = *(const float4*)s;
            wv[j][1] = *(const float4*)(s + 4);
        }
        __syncthreads();
#pragma unroll
        for (int j = 0; j < 4; j++)
            *(uint4*)(lds + GS + (rw + 32 * j) * 128 + dcol) = gv[j];
#pragma unroll
        for (int j = 0; j < 4; j++)
            *(uint4*)(lds + W2S + (rw + 32 * j) * 128 + dcol) = pack8(wv[j][0], wv[j][1]);
        __syncthreads();
#pragma unroll
        for (int s = 0; s < 4; s++) {
            const unsigned int off = ((unsigned)(s * 32) + hi16) ^ lswz;
            bf16x8 a0 = *(const bf16x8*)(lds + aBase + off);
            bf16x8 a1 = *(const bf16x8*)(lds + aBase + 32 * 128 + off);
            bf16x8 b0 = *(const bf16x8*)(lds + bBase + off);
            bf16x8 b1 = *(const bf16x8*)(lds + bBase + 32 * 128 + off);
            acc[0][0] = __builtin_amdgcn_mfma_f32_32x32x16_bf16(a0, b0, acc[0][0], 0, 0, 0);
            acc[0][1] = __builtin_amdgcn_mfma_f32_32x32x16_bf16(a0, b1, acc[0][1], 0, 0, 0);
            acc[1][0] = __builtin_amdgcn_mfma_f32_32x32x16_bf16(a1, b0, acc[1][0], 0, 0, 0);
            acc[1][1] = __builtin_amdgcn_mfma_f32_32x32x16_bf16(a1, b1, acc[1][1], 0, 0, 0);
        }
    }

    const int rbase = 4 * (lane >> 5);
#pragma unroll
    for (int ma = 0; ma < 2; ma++) {
#pragma unroll
        for (int r = 0; r < 16; r++) {
            int row = (r & 3) + 8 * (r >> 2) + rbase;
            int m = wr * 64 + ma * 32 + row;
            if (m0 + m < cntE) {
                int t = toks_s[m];
                float wgt = gws_s[m];
                float* orow = out + (size_t)t * HDIM + h0 + wc * 64 + lrow;
                atomicAdd(&orow[0],  wgt * acc[ma][0][r]);
                atomicAdd(&orow[32], wgt * acc[ma][1][r]);
            }
        }
    }
}

extern "C" void kernel_launch(void* const* d_in, const int* in_sizes, int n_in,
                              void* d_out, int out_size, void* d_ws, size_t ws_size,
                              hipStream_t stream) {
    const float* x      = (const float*)d_in[0];
    const float* gate_w = (const float*)d_in[1];
    const float* w1     = (const float*)d_in[2];
    const float* w2     = (const float*)d_in[3];
    const float* w3     = (const float*)d_in[4];
    float* out = (float*)d_out;
    char* ws = (char*)d_ws;
    int* cnt   = (int*)(ws + WS_CNT);
    int* base  = (int*)(ws + WS_BASE);
    int* tileE = (int*)(ws + WS_TE);
    int* tileM = (int*)(ws + WS_TM);
    int* ntot  = (int*)(ws + WS_NT);
    int* tok   = (int*)(ws + WS_TOK);
    float* gw  = (float*)(ws + WS_GW);
    unsigned short* xb = (unsigned short*)(ws + WS_XB);
    unsigned short* g  = (unsigned short*)(ws + WS_G);

    hipMemsetAsync(cnt, 0, 64, stream);
    hipMemsetAsync(d_out, 0, (size_t)out_size * sizeof(float), stream);

    xcvt_kernel<<<T_TOK * HDIM / (256 * 8), 256, 0, stream>>>(x, xb);
    router_kernel<<<T_TOK / 4, 256, 0, stream>>>(x, gate_w, cnt, tok, gw);
    scan_kernel<<<1, 64, 0, stream>>>(cnt, base, tileE, tileM, ntot);
    ffn1_mfma<<<dim3(IDIM / 128, MAXTILE), 256, 0, stream>>>(xb, w1, w3, cnt, base, tok, tileE, tileM, ntot, g);
    ffn2_mfma<<<dim3(32, MAXTILE), 256, 0, stream>>>(g, w2, cnt, base, tok, gw, tileE, tileM, ntot, out);
}